// Round 1
// baseline (317.203 us; speedup 1.0000x reference)
//
#include <hip/hip_runtime.h>
#include <math.h>

namespace {

constexpr int Bsz = 16384;
constexpr int T   = 200;
constexpr int F   = 4;
constexpr int H   = 10;

// tanh(x) = 1 - 2/(exp(2x)+1); saturates correctly to +/-1 for |x| large.
__device__ __forceinline__ float fast_tanh(float x) {
  float e = exp2f(x * 2.8853900817779268f);   // exp(2x) via v_exp_f32
  return 1.0f - 2.0f * __builtin_amdgcn_rcpf(e + 1.0f);
}

__device__ __forceinline__ float fast_sigmoid(float x) {
  float e = exp2f(x * -1.4426950408889634f);  // exp(-x)
  return __builtin_amdgcn_rcpf(1.0f + e);
}

__global__ __launch_bounds__(64, 1) void rnn2_fused(
    const float* __restrict__ x,
    const float* __restrict__ W_ih0, const float* __restrict__ W_hh0,
    const float* __restrict__ b_ih0, const float* __restrict__ b_hh0,
    const float* __restrict__ W_ih1, const float* __restrict__ W_hh1,
    const float* __restrict__ b_ih1, const float* __restrict__ b_hh1,
    const float* __restrict__ W_fc, const float* __restrict__ b_fc,
    float* __restrict__ out) {
  // Stage the per-timestep FC weights in LDS (uniform broadcast reads in loop).
  __shared__ float s_wfc[T * H];
  for (int i = threadIdx.x; i < T * H; i += 64) s_wfc[i] = W_fc[i];
  __syncthreads();

  const int b = blockIdx.x * 64 + threadIdx.x;
  const float4* __restrict__ xrow =
      reinterpret_cast<const float4*>(x + (size_t)b * (T * F));

  float h0[H], h1[H];
#pragma unroll
  for (int h = 0; h < H; ++h) { h0[h] = 0.0f; h1[h] = 0.0f; }
  float acc = 0.0f;

  float4 xv = xrow[0];  // current timestep's input (prefetched)
#pragma unroll 1
  for (int t = 0; t < T; ++t) {
    float4 xnext = (t + 1 < T) ? xrow[t + 1] : xv;  // software prefetch

    // layer 0: a0 = b_ih0 + b_hh0 + W_ih0 @ x_t + W_hh0 @ h0_prev
    float a0[H];
#pragma unroll
    for (int h = 0; h < H; ++h) {
      float s = b_ih0[h] + b_hh0[h];
      s = fmaf(W_ih0[h * F + 0], xv.x, s);
      s = fmaf(W_ih0[h * F + 1], xv.y, s);
      s = fmaf(W_ih0[h * F + 2], xv.z, s);
      s = fmaf(W_ih0[h * F + 3], xv.w, s);
#pragma unroll
      for (int j = 0; j < H; ++j) s = fmaf(W_hh0[h * H + j], h0[j], s);
      a0[h] = s;
    }
#pragma unroll
    for (int h = 0; h < H; ++h) h0[h] = fast_tanh(a0[h]);

    // layer 1: a1 = b_ih1 + b_hh1 + W_ih1 @ h0_new + W_hh1 @ h1_prev
    float a1[H];
#pragma unroll
    for (int h = 0; h < H; ++h) {
      float s = b_ih1[h] + b_hh1[h];
#pragma unroll
      for (int j = 0; j < H; ++j) s = fmaf(W_ih1[h * H + j], h0[j], s);
#pragma unroll
      for (int j = 0; j < H; ++j) s = fmaf(W_hh1[h * H + j], h1[j], s);
      a1[h] = s;
    }
    // update h1 and fuse the FC-head dot product
#pragma unroll
    for (int h = 0; h < H; ++h) {
      float v = fast_tanh(a1[h]);
      h1[h] = v;
      acc = fmaf(v, s_wfc[t * H + h], acc);
    }
    xv = xnext;
  }

  out[b] = fast_sigmoid(acc + b_fc[0]);
}

}  // namespace

extern "C" void kernel_launch(void* const* d_in, const int* in_sizes, int n_in,
                              void* d_out, int out_size, void* d_ws, size_t ws_size,
                              hipStream_t stream) {
  const float* x     = (const float*)d_in[0];
  const float* W_ih0 = (const float*)d_in[1];
  const float* W_hh0 = (const float*)d_in[2];
  const float* b_ih0 = (const float*)d_in[3];
  const float* b_hh0 = (const float*)d_in[4];
  const float* W_ih1 = (const float*)d_in[5];
  const float* W_hh1 = (const float*)d_in[6];
  const float* b_ih1 = (const float*)d_in[7];
  const float* b_hh1 = (const float*)d_in[8];
  const float* W_fc  = (const float*)d_in[9];
  const float* b_fc  = (const float*)d_in[10];
  float* out = (float*)d_out;

  dim3 grid(Bsz / 64), block(64);
  hipLaunchKernelGGL(rnn2_fused, grid, block, 0, stream,
                     x, W_ih0, W_hh0, b_ih0, b_hh0,
                     W_ih1, W_hh1, b_ih1, b_hh1, W_fc, b_fc, out);
}